// Round 1
// baseline (308.923 us; speedup 1.0000x reference)
//
#include <hip/hip_runtime.h>
#include <math.h>

#define EPSF 1e-9f
#define SS 20
#define KK 128
#define NPK 128   // N - K
#define MTOP 10   // m

__device__ __forceinline__ float max8(const float v[8]) {
    float a = fmaxf(v[0], v[1]), b = fmaxf(v[2], v[3]);
    float c = fmaxf(v[4], v[5]), d = fmaxf(v[6], v[7]);
    return fmaxf(fmaxf(a, b), fmaxf(c, d));
}

// One wave (64 lanes) handles one batch element b.
// lanes: jg = lane&31 -> output columns [4jg, 4jg+4)  (of the 128 computed cols)
//        sg = lane>>5 -> samples [10sg, 10sg+10)
__global__ __launch_bounds__(256) void fused_kernel(
    const float* __restrict__ y_pred, const float* __restrict__ y_true,
    const float* __restrict__ P, const float* __restrict__ samples,
    float* __restrict__ accum /* [0]=logmse_sum, [1]=penalty_sum */)
{
    const int wid  = threadIdx.x >> 6;
    const int lane = threadIdx.x & 63;
    const int b    = blockIdx.x * 4 + wid;
    const int jg   = lane & 31;
    const int sg   = lane >> 5;
    const int j4   = jg << 2;
    const int s0   = sg * 10;

    const float* __restrict__ Pb = P + ((size_t)b << 14);            // b*128*128
    const float* __restrict__ Sb = samples + (size_t)b * (SS * KK);  // b*20*128

    float4 acc[10];
    #pragma unroll
    for (int i = 0; i < 10; ++i) acc[i] = make_float4(0.f, 0.f, 0.f, 0.f);

    // ---- GEMM phase: acc[i][jj] = sum_k samples[s0+i][k] * P[k][j4+jj] ----
    #pragma unroll 2
    for (int k0 = 0; k0 < KK; k0 += 4) {
        float4 sv[10];
        #pragma unroll
        for (int i = 0; i < 10; ++i)
            sv[i] = *(const float4*)(Sb + (s0 + i) * KK + k0);
        #pragma unroll
        for (int kk = 0; kk < 4; ++kk) {
            float4 p = *(const float4*)(Pb + (size_t)(k0 + kk) * NPK + j4);
            #pragma unroll
            for (int i = 0; i < 10; ++i) {
                float s = (kk == 0) ? sv[i].x : (kk == 1) ? sv[i].y
                        : (kk == 2) ? sv[i].z : sv[i].w;
                acc[i].x = fmaf(s, p.x, acc[i].x);
                acc[i].y = fmaf(s, p.y, acc[i].y);
                acc[i].z = fmaf(s, p.z, acc[i].z);
                acc[i].w = fmaf(s, p.w, acc[i].w);
            }
        }
    }

    // ---- Top-11 per sample row (within a half-wave: 32 lanes x 8 vals = 256) ----
    const unsigned long long halfmask =
        sg ? 0xFFFFFFFF00000000ull : 0x00000000FFFFFFFFull;
    float hmax = 0.f;

    #pragma unroll 1
    for (int i = 0; i < 10; ++i) {
        // identity part of G: codeword[:128] == samples row -> |samples|
        float4 vs = *(const float4*)(Sb + (s0 + i) * KK + j4);
        float v[8];
        v[0] = fabsf(acc[i].x); v[1] = fabsf(acc[i].y);
        v[2] = fabsf(acc[i].z); v[3] = fabsf(acc[i].w);
        v[4] = fabsf(vs.x);     v[5] = fabsf(vs.y);
        v[6] = fabsf(vs.z);     v[7] = fabsf(vs.w);

        float m1 = 0.f, m11 = 0.f;
        #pragma unroll 1
        for (int it = 0; it <= MTOP; ++it) {
            float lm = max8(v);
            float Mx = lm;
            #pragma unroll
            for (int d = 16; d >= 1; d >>= 1)
                Mx = fmaxf(Mx, __shfl_xor(Mx, d, 32));
            if (it == 0) m1 = Mx;
            if (it == MTOP) { m11 = Mx; break; }
            // remove exactly one instance of Mx (in the first lane holding it)
            unsigned long long ball = __ballot(lm == Mx) & halfmask;
            int first = __ffsll(ball) - 1;
            if (lane == first) {
                bool done = false;
                #pragma unroll
                for (int r = 0; r < 8; ++r) {
                    bool hit = (!done) && (v[r] == Mx);
                    v[r] = hit ? -1.f : v[r];
                    done = done || hit;
                }
            }
        }
        float hm = m1 / (m11 + EPSF);
        hmax = fmaxf(hmax, hm);
    }
    // combine the two half-waves (s 0..9 vs s 10..19)
    hmax = fmaxf(hmax, __shfl_xor(hmax, 32, 64));

    // ---- per-block reduction, then global atomics ----
    __shared__ float red_lms[4];
    __shared__ float red_pen[4];
    if (lane == 0) {
        float ypv = y_pred[b];
        float yp = fmaxf(ypv, EPSF);
        float yt = fmaxf(y_true[b], EPSF);
        float d = log2f(yt) - log2f(yp);
        red_lms[wid] = d * d;
        red_pen[wid] = fmaxf(hmax - ypv, 0.f);
    }
    __syncthreads();
    if (threadIdx.x == 0) {
        atomicAdd(&accum[0], red_lms[0] + red_lms[1] + red_lms[2] + red_lms[3]);
        atomicAdd(&accum[1], red_pen[0] + red_pen[1] + red_pen[2] + red_pen[3]);
    }
}

__global__ void finalize_kernel(const float* __restrict__ accum,
                                float* __restrict__ out, float invB)
{
    if (threadIdx.x == 0) {
        float logmse    = accum[0] * invB;
        float violation = accum[1] * invB;
        out[0] = logmse + 0.5f * violation;
        out[1] = logmse;
        out[2] = violation;
    }
}

extern "C" void kernel_launch(void* const* d_in, const int* in_sizes, int n_in,
                              void* d_out, int out_size, void* d_ws, size_t ws_size,
                              hipStream_t stream) {
    const float* y_pred  = (const float*)d_in[0];
    const float* y_true  = (const float*)d_in[1];
    const float* P       = (const float*)d_in[2];
    const float* samples = (const float*)d_in[3];
    const int B = in_sizes[0];           // y_pred has B elements

    float* accum = (float*)d_ws;
    hipMemsetAsync(accum, 0, 2 * sizeof(float), stream);

    fused_kernel<<<B / 4, 256, 0, stream>>>(y_pred, y_true, P, samples, accum);
    finalize_kernel<<<1, 64, 0, stream>>>(accum, (float*)d_out, 1.0f / (float)B);
}